// Round 9
// baseline (126.055 us; speedup 1.0000x reference)
//
#include <hip/hip_runtime.h>

#define HH 512
#define WW 512
#define RSTRIP 16          // output rows per block (2048 blocks, 32 strips/image)
#define PWC 520            // padded VS row: [4 zeros][512][4 zeros]

// NCC via register-resident vertical column sums (VS) + LDS horizontal fold.
// Block = 128 threads (2 waves); lane owns 4 cols (c0 = 4T). Per step:
//   write VS -> LDS (dbuf), 1 barrier, read 12-col window (3x b128), fold
//   9-wide fresh (no running box chain), cc, VS += lead - trail products.
// Lead/trail rows come from direct aligned float4 loads (trail is L1/L2-hot).
__global__ __launch_bounds__(128) void ncc_kernel(const float* __restrict__ I,
                                                  const float* __restrict__ J,
                                                  float* __restrict__ ws) {
    __shared__ float vs[2][5][PWC];             // 20,800 B
    const int T = threadIdx.x;                  // owns cols 4T..4T+3
    const int c0 = T << 2;
    const int b = blockIdx.x >> 5;              // image
    const int r0 = (blockIdx.x & 31) << 4;      // strip base row

    const float* Ib = I + (size_t)b * (HH * WW);
    const float* Jb = J + (size_t)b * (HH * WW);

    // zero the column pads once: 2 bufs x 5 products x 8 pad floats = 80
    if (T < 80) {
        const int buf = T / 40, rem = T % 40, p = rem >> 3, k = rem & 7;
        vs[buf][p][(k < 4) ? k : (512 + k)] = 0.f;
    }

    // warm-up: VS = sum of products over rows r0-4 .. r0+4 (uniform skip)
    float VS[5][4] = {{0.f}};
    for (int j = r0 - 4; j <= r0 + 4; ++j) {
        if (j >= 0) {
            float4 iv = *reinterpret_cast<const float4*>(Ib + (size_t)j * WW + c0);
            float4 jv = *reinterpret_cast<const float4*>(Jb + (size_t)j * WW + c0);
            const float pi[4] = {iv.x, iv.y, iv.z, iv.w};
            const float pj[4] = {jv.x, jv.y, jv.z, jv.w};
#pragma unroll
            for (int c = 0; c < 4; ++c) {
                VS[0][c] += pi[c];
                VS[1][c] += pj[c];
                VS[2][c] = fmaf(pi[c], pi[c], VS[2][c]);
                VS[3][c] = fmaf(pj[c], pj[c], VS[3][c]);
                VS[4][c] = fmaf(pi[c], pj[c], VS[4][c]);
            }
        }
    }

    // prefetch lead row r0+5 (always < HH) and trail row r0-4 (clamped)
    float4 Li = *reinterpret_cast<const float4*>(Ib + (size_t)(r0 + 5) * WW + c0);
    float4 Lj = *reinterpret_cast<const float4*>(Jb + (size_t)(r0 + 5) * WW + c0);
    float4 Ti, Tj;
    {
        const int jt = (r0 - 4) < 0 ? 0 : (r0 - 4);
        Ti = *reinterpret_cast<const float4*>(Ib + (size_t)jt * WW + c0);
        Tj = *reinterpret_cast<const float4*>(Jb + (size_t)jt * WW + c0);
    }

    const float inv81 = 1.f / 81.f;
    float acc = 0.f;

    for (int h = 0; h < RSTRIP; ++h) {
        // 1. publish VS for output row r0+h
#pragma unroll
        for (int p = 0; p < 5; ++p)
            *reinterpret_cast<float4*>(&vs[h & 1][p][4 + c0]) =
                make_float4(VS[p][0], VS[p][1], VS[p][2], VS[p][3]);

        // 2. issue next step's lead/trail loads (consumed after fold+cc)
        const int jl = r0 + h + 6, jt = r0 + h - 3;
        const int jlc = jl > HH - 1 ? HH - 1 : jl;
        const int jtc = jt < 0 ? 0 : jt;
        float4 nLi = *reinterpret_cast<const float4*>(Ib + (size_t)jlc * WW + c0);
        float4 nLj = *reinterpret_cast<const float4*>(Jb + (size_t)jlc * WW + c0);
        float4 nTi = *reinterpret_cast<const float4*>(Ib + (size_t)jtc * WW + c0);
        float4 nTj = *reinterpret_cast<const float4*>(Jb + (size_t)jtc * WW + c0);

        __syncthreads();                        // vs[h&1] fully written

        // 3. 12-col window read + fresh 9-wide fold -> box for 4 output cols
        float box[5][4];
#pragma unroll
        for (int p = 0; p < 5; ++p) {
            const float4* q =
                reinterpret_cast<const float4*>(&vs[h & 1][p][c0]);
            float4 w0 = q[0], w1 = q[1], w2 = q[2];
            const float w[12] = {w0.x, w0.y, w0.z, w0.w, w1.x, w1.y, w1.z, w1.w,
                                 w2.x, w2.y, w2.z, w2.w};
            float s = (((w[0] + w[1]) + (w[2] + w[3])) +
                       ((w[4] + w[5]) + (w[6] + w[7]))) + w[8];
            box[p][0] = s;
            s += w[9] - w[0];  box[p][1] = s;
            s += w[10] - w[1]; box[p][2] = s;
            s += w[11] - w[2]; box[p][3] = s;
        }
#pragma unroll
        for (int o = 0; o < 4; ++o) {
            float IS = box[0][o], JS = box[1][o];
            float I2 = box[2][o], J2 = box[3][o], IJ = box[4][o];
            float cross = fmaf(-(IS * JS), inv81, IJ);
            float Iv = fmaf(-(IS * IS), inv81, I2);
            float Jv = fmaf(-(JS * JS), inv81, J2);
            acc = fmaf(cross * cross,
                       __builtin_amdgcn_rcpf(fmaf(Iv, Jv, 1e-5f)), acc);
        }

        // 4. VS update for next row (block-uniform validity branches)
        if (r0 + h + 5 < HH) {
            const float pi[4] = {Li.x, Li.y, Li.z, Li.w};
            const float pj[4] = {Lj.x, Lj.y, Lj.z, Lj.w};
#pragma unroll
            for (int c = 0; c < 4; ++c) {
                VS[0][c] += pi[c];
                VS[1][c] += pj[c];
                VS[2][c] = fmaf(pi[c], pi[c], VS[2][c]);
                VS[3][c] = fmaf(pj[c], pj[c], VS[3][c]);
                VS[4][c] = fmaf(pi[c], pj[c], VS[4][c]);
            }
        }
        if (r0 + h - 4 >= 0) {
            const float pi[4] = {Ti.x, Ti.y, Ti.z, Ti.w};
            const float pj[4] = {Tj.x, Tj.y, Tj.z, Tj.w};
#pragma unroll
            for (int c = 0; c < 4; ++c) {
                VS[0][c] -= pi[c];
                VS[1][c] -= pj[c];
                VS[2][c] = fmaf(-pi[c], pi[c], VS[2][c]);
                VS[3][c] = fmaf(-pj[c], pj[c], VS[3][c]);
                VS[4][c] = fmaf(-pi[c], pj[c], VS[4][c]);
            }
        }
        Li = nLi; Lj = nLj; Ti = nTi; Tj = nTj;
    }

    // block reduction (2 waves)
#pragma unroll
    for (int off = 32; off; off >>= 1) acc += __shfl_down(acc, off);
    __syncthreads();
    if ((T & 63) == 0) vs[0][0][T >> 6] = acc;
    __syncthreads();
    if (T == 0) atomicAdd(&ws[0], vs[0][0][0] + vs[0][0][1]);
}

// reg: EXACT R6/R8 configuration (measured ~21-22 us): 1024 blocks, 32-row
// register-carried strips, 2 strips per 256-thread block.
__global__ __launch_bounds__(256) void reg_kernel(const float* __restrict__ P,
                                                  float* __restrict__ ws) {
    __shared__ float sh[8];
    const int T = threadIdx.x;
    const int c4 = T & 127;                         // 128 float4s = one row
    const int strip = (blockIdx.x << 1) | (T >> 7); // 0..2047 over 65536 rows
    const size_t row0 = (size_t)strip << 5;         // *32 rows per strip
    const bool slast = ((strip & 15) == 15);        // ends at image row 511
    const float* rp = P + row0 * WW + (c4 << 2);

    float sdx = 0.f, sdy = 0.f;
    float4 cur = *reinterpret_cast<const float4*>(rp);
#pragma unroll 8
    for (int i = 0; i < 32; ++i) {
        float d0 = cur.y - cur.x, d1 = cur.z - cur.y, d2 = cur.w - cur.z;
        sdx += d0 * d0 + d1 * d1 + d2 * d2;
        if (c4 < 127) {                             // neighbor elem (cache hit)
            float nx = rp[(size_t)i * WW + 4];
            float d3 = nx - cur.w;
            sdx += d3 * d3;
        }
        if (i < 31) {
            float4 nr = *reinterpret_cast<const float4*>(rp + (size_t)(i + 1) * WW);
            float e0 = nr.x - cur.x, e1 = nr.y - cur.y;
            float e2 = nr.z - cur.z, e3 = nr.w - cur.w;
            sdy += e0 * e0 + e1 * e1 + e2 * e2 + e3 * e3;
            cur = nr;
        } else if (!slast) {
            float4 nr = *reinterpret_cast<const float4*>(rp + (size_t)32 * WW);
            float e0 = nr.x - cur.x, e1 = nr.y - cur.y;
            float e2 = nr.z - cur.z, e3 = nr.w - cur.w;
            sdy += e0 * e0 + e1 * e1 + e2 * e2 + e3 * e3;
        }
    }

#pragma unroll
    for (int off = 32; off; off >>= 1) {
        sdx += __shfl_down(sdx, off);
        sdy += __shfl_down(sdy, off);
    }
    if ((T & 63) == 0) { sh[T >> 6] = sdx; sh[4 + (T >> 6)] = sdy; }
    __syncthreads();
    if (T == 0) {
        atomicAdd(&ws[1], sh[0] + sh[1] + sh[2] + sh[3]);
        atomicAdd(&ws[2], sh[4] + sh[5] + sh[6] + sh[7]);
    }
}

__global__ void finalize_kernel(const float* __restrict__ ws,
                                float* __restrict__ out) {
    float cc_sum = ws[0], dx_sum = ws[1], dy_sum = ws[2];
    float loss_sim = -(cc_sum / 16777216.f);   // 64*512*512
    float mdx = dx_sum / 33488896.f;           // 64*2*512*511
    float mdy = dy_sum / 33488896.f;           // 64*2*511*512
    float loss_reg = (mdx + mdy) * 0.5f * 0.1f;
    out[0] = loss_sim;
    out[1] = loss_reg;
    out[2] = loss_sim + loss_reg;
}

extern "C" void kernel_launch(void* const* d_in, const int* in_sizes, int n_in,
                              void* d_out, int out_size, void* d_ws, size_t ws_size,
                              hipStream_t stream) {
    const float* I = (const float*)d_in[0];   // target_proj
    const float* J = (const float*)d_in[1];   // warped_moving
    const float* P = (const float*)d_in[2];   // phi
    float* out = (float*)d_out;
    float* ws = (float*)d_ws;

    hipMemsetAsync(d_ws, 0, 3 * sizeof(float), stream);
    ncc_kernel<<<2048, 128, 0, stream>>>(I, J, ws);  // 8 blocks/CU, 20.8 KB LDS
    reg_kernel<<<1024, 256, 0, stream>>>(P, ws);     // R6 config, ~21 us
    finalize_kernel<<<1, 1, 0, stream>>>(ws, out);
}

// Round 10
// 103.118 us; speedup vs baseline: 1.2224x; 1.2224x over previous
//
#include <hip/hip_runtime.h>

#define HH 512
#define WW 512
#define RSTRIP 16          // output rows per block (2048 blocks, 32 strips/image)
#define PWC 520            // padded VS row: [4 zeros][512][4 zeros]

// NCC, register-history edition.
//  - 256 threads/block (4 waves); lane owns 2 cols (c0 = 2T); block = 16-row strip.
//  - Raw I/J rows live in an 11-deep per-lane register ring (float2). Trail
//    products are recomputed from registers: NO trail re-loads, ever.
//  - Per step the only global traffic is 2 float2 lead loads, prefetched
//    2 steps (~1000 cy) ahead of use.
//  - Horizontal 9-window via LDS fold of the 5 vertical sums (double-buffered,
//    one barrier/step, aligned float2 ops -> 2 lanes/bank = conflict-free).
__global__ __launch_bounds__(256) void ncc_kernel(const float* __restrict__ I,
                                                  const float* __restrict__ J,
                                                  float* __restrict__ ws) {
    __shared__ float vs[2][5][PWC];             // 20,800 B -> 7 blocks/CU
    const int T = threadIdx.x;                  // owns cols 2T, 2T+1
    const int c0 = T << 1;
    const int b = blockIdx.x >> 5;              // image
    const int r0 = (blockIdx.x & 31) << 4;      // strip base row

    const float* Ib = I + (size_t)b * (HH * WW);
    const float* Jb = J + (size_t)b * (HH * WW);

    // zero the column pads once: 2 bufs x 5 products x 8 pad floats = 80
    if (T < 80) {
        const int buf = T / 40, rem = T % 40, p = rem >> 3, k = rem & 7;
        vs[buf][p][(k < 4) ? k : (512 + k)] = 0.f;
    }

    // ---- register history ring: slot s holds row r0+s-4 (s = 0..10) ----
    float2 hi[11], hj[11];
#pragma unroll
    for (int s = 0; s < 11; ++s) {
        const int r = r0 + s - 4;               // r0+6 <= 502: no high clamp
        if (r >= 0) {                           // uniform branch
            hi[s] = *reinterpret_cast<const float2*>(Ib + (size_t)r * WW + c0);
            hj[s] = *reinterpret_cast<const float2*>(Jb + (size_t)r * WW + c0);
        } else {                                // zero-pad above the image
            hi[s] = make_float2(0.f, 0.f);
            hj[s] = make_float2(0.f, 0.f);
        }
    }

    // ---- warm-up: VS = sum of products over slots 0..8 (rows r0-4..r0+4) ----
    float VS[5][2] = {{0.f, 0.f}};
#pragma unroll
    for (int s = 0; s <= 8; ++s) {              // zeros contribute nothing
        const float i0 = hi[s].x, i1 = hi[s].y;
        const float j0 = hj[s].x, j1 = hj[s].y;
        VS[0][0] += i0;                 VS[0][1] += i1;
        VS[1][0] += j0;                 VS[1][1] += j1;
        VS[2][0] = fmaf(i0, i0, VS[2][0]); VS[2][1] = fmaf(i1, i1, VS[2][1]);
        VS[3][0] = fmaf(j0, j0, VS[3][0]); VS[3][1] = fmaf(j1, j1, VS[3][1]);
        VS[4][0] = fmaf(i0, j0, VS[4][0]); VS[4][1] = fmaf(i1, j1, VS[4][1]);
    }

    const float inv81 = 1.f / 81.f;
    float acc = 0.f;

#pragma unroll
    for (int h = 0; h < RSTRIP; ++h) {          // FULL unroll: ring indices static
        // 1. publish VS for output row r0+h
#pragma unroll
        for (int p = 0; p < 5; ++p)
            *reinterpret_cast<float2*>(&vs[h & 1][p][4 + c0]) =
                make_float2(VS[p][0], VS[p][1]);

        // 2. prefetch row r0+h+7 (lead for step h+2); clamp only matters for
        //    rows never consumed (gated adds / trail beyond step 15)
        const int rp = (r0 + h + 7 > HH - 1) ? HH - 1 : (r0 + h + 7);
        float2 nLi = *reinterpret_cast<const float2*>(Ib + (size_t)rp * WW + c0);
        float2 nLj = *reinterpret_cast<const float2*>(Jb + (size_t)rp * WW + c0);

        __syncthreads();                        // vs[h&1] fully written

        // 3. window read (5 aligned float2s = floats c0..c0+9 of padded row)
        //    + fresh 9-wide fold -> box for 2 output cols
        float box[5][2];
#pragma unroll
        for (int p = 0; p < 5; ++p) {
            const float2* q = reinterpret_cast<const float2*>(&vs[h & 1][p][0]) + T;
            float2 a = q[0], bb = q[1], c = q[2], d = q[3], e = q[4];
            float s = (((a.x + a.y) + (bb.x + bb.y)) +
                       ((c.x + c.y) + (d.x + d.y))) + e.x;
            box[p][0] = s;
            box[p][1] = s + (e.y - a.x);
        }
#pragma unroll
        for (int o = 0; o < 2; ++o) {
            const float IS = box[0][o], JS = box[1][o];
            const float I2 = box[2][o], J2 = box[3][o], IJ = box[4][o];
            const float cross = fmaf(-(IS * JS), inv81, IJ);
            const float Iv = fmaf(-(IS * IS), inv81, I2);
            const float Jv = fmaf(-(JS * JS), inv81, J2);
            acc = fmaf(cross * cross,
                       __builtin_amdgcn_rcpf(fmaf(Iv, Jv, 1e-5f)), acc);
        }

        // 4. VS update for next output row
        //    lead = slot (h+9)%11 (row r0+h+5), gated at the image bottom
        if (r0 + h + 5 < HH) {                  // uniform branch
            const float2 li = hi[(h + 9) % 11], lj = hj[(h + 9) % 11];
            VS[0][0] += li.x;                 VS[0][1] += li.y;
            VS[1][0] += lj.x;                 VS[1][1] += lj.y;
            VS[2][0] = fmaf(li.x, li.x, VS[2][0]); VS[2][1] = fmaf(li.y, li.y, VS[2][1]);
            VS[3][0] = fmaf(lj.x, lj.x, VS[3][0]); VS[3][1] = fmaf(lj.y, lj.y, VS[3][1]);
            VS[4][0] = fmaf(li.x, lj.x, VS[4][0]); VS[4][1] = fmaf(li.y, lj.y, VS[4][1]);
        }
        //    trail = slot h%11 (row r0+h-4); negative rows are zeros -> no gate
        {
            const float2 ti = hi[h % 11], tj = hj[h % 11];
            VS[0][0] -= ti.x;                 VS[0][1] -= ti.y;
            VS[1][0] -= tj.x;                 VS[1][1] -= tj.y;
            VS[2][0] = fmaf(-ti.x, ti.x, VS[2][0]); VS[2][1] = fmaf(-ti.y, ti.y, VS[2][1]);
            VS[3][0] = fmaf(-tj.x, tj.x, VS[3][0]); VS[3][1] = fmaf(-tj.y, tj.y, VS[3][1]);
            VS[4][0] = fmaf(-ti.x, tj.x, VS[4][0]); VS[4][1] = fmaf(-ti.y, tj.y, VS[4][1]);
        }
        //    commit prefetch into the slot the trail just freed
        hi[h % 11] = nLi;
        hj[h % 11] = nLj;
    }

    // block reduction (4 waves)
#pragma unroll
    for (int off = 32; off; off >>= 1) acc += __shfl_down(acc, off);
    __syncthreads();
    if ((T & 63) == 0) vs[0][0][T >> 6] = acc;
    __syncthreads();
    if (T == 0)
        atomicAdd(&ws[0], (vs[0][0][0] + vs[0][0][1]) +
                          (vs[0][0][2] + vs[0][0][3]));
}

// reg: EXACT R6/R8 configuration (measured ~21-22 us): 1024 blocks, 32-row
// register-carried strips, 2 strips per 256-thread block.
__global__ __launch_bounds__(256) void reg_kernel(const float* __restrict__ P,
                                                  float* __restrict__ ws) {
    __shared__ float sh[8];
    const int T = threadIdx.x;
    const int c4 = T & 127;                         // 128 float4s = one row
    const int strip = (blockIdx.x << 1) | (T >> 7); // 0..2047 over 65536 rows
    const size_t row0 = (size_t)strip << 5;         // *32 rows per strip
    const bool slast = ((strip & 15) == 15);        // ends at image row 511
    const float* rp = P + row0 * WW + (c4 << 2);

    float sdx = 0.f, sdy = 0.f;
    float4 cur = *reinterpret_cast<const float4*>(rp);
#pragma unroll 8
    for (int i = 0; i < 32; ++i) {
        float d0 = cur.y - cur.x, d1 = cur.z - cur.y, d2 = cur.w - cur.z;
        sdx += d0 * d0 + d1 * d1 + d2 * d2;
        if (c4 < 127) {                             // neighbor elem (cache hit)
            float nx = rp[(size_t)i * WW + 4];
            float d3 = nx - cur.w;
            sdx += d3 * d3;
        }
        if (i < 31) {
            float4 nr = *reinterpret_cast<const float4*>(rp + (size_t)(i + 1) * WW);
            float e0 = nr.x - cur.x, e1 = nr.y - cur.y;
            float e2 = nr.z - cur.z, e3 = nr.w - cur.w;
            sdy += e0 * e0 + e1 * e1 + e2 * e2 + e3 * e3;
            cur = nr;
        } else if (!slast) {
            float4 nr = *reinterpret_cast<const float4*>(rp + (size_t)32 * WW);
            float e0 = nr.x - cur.x, e1 = nr.y - cur.y;
            float e2 = nr.z - cur.z, e3 = nr.w - cur.w;
            sdy += e0 * e0 + e1 * e1 + e2 * e2 + e3 * e3;
        }
    }

#pragma unroll
    for (int off = 32; off; off >>= 1) {
        sdx += __shfl_down(sdx, off);
        sdy += __shfl_down(sdy, off);
    }
    if ((T & 63) == 0) { sh[T >> 6] = sdx; sh[4 + (T >> 6)] = sdy; }
    __syncthreads();
    if (T == 0) {
        atomicAdd(&ws[1], sh[0] + sh[1] + sh[2] + sh[3]);
        atomicAdd(&ws[2], sh[4] + sh[5] + sh[6] + sh[7]);
    }
}

__global__ void finalize_kernel(const float* __restrict__ ws,
                                float* __restrict__ out) {
    float cc_sum = ws[0], dx_sum = ws[1], dy_sum = ws[2];
    float loss_sim = -(cc_sum / 16777216.f);   // 64*512*512
    float mdx = dx_sum / 33488896.f;           // 64*2*512*511
    float mdy = dy_sum / 33488896.f;           // 64*2*511*512
    float loss_reg = (mdx + mdy) * 0.5f * 0.1f;
    out[0] = loss_sim;
    out[1] = loss_reg;
    out[2] = loss_sim + loss_reg;
}

extern "C" void kernel_launch(void* const* d_in, const int* in_sizes, int n_in,
                              void* d_out, int out_size, void* d_ws, size_t ws_size,
                              hipStream_t stream) {
    const float* I = (const float*)d_in[0];   // target_proj
    const float* J = (const float*)d_in[1];   // warped_moving
    const float* P = (const float*)d_in[2];   // phi
    float* out = (float*)d_out;
    float* ws = (float*)d_ws;

    hipMemsetAsync(d_ws, 0, 3 * sizeof(float), stream);
    ncc_kernel<<<2048, 256, 0, stream>>>(I, J, ws);  // 7 blocks/CU, 20.8 KB LDS
    reg_kernel<<<1024, 256, 0, stream>>>(P, ws);     // R6 config, ~21 us
    finalize_kernel<<<1, 1, 0, stream>>>(ws, out);
}